// Round 7
// baseline (3145.454 us; speedup 1.0000x reference)
//
#include <hip/hip_runtime.h>
#include <hip/hip_fp16.h>

// B=256, T=512, F=16, H=256, L=2 LSTM + gather(len-1) + ReLU + FC(256->1).
//
// R7: R6's 3-role pipelined launches + PARTIAL REGISTER RESIDENCY of the
// recurrent weights: each thread keeps 32 of its 64 k-pairs in VGPRs
// (128 VGPR, loaded once per launch) and streams only the other 32
// (256 KB/step/block instead of 512 KB -> halves the per-CU L2 wall).
//   blocks   0..85 : l0 recurrence, chunk k
//   blocks  86..171: l1 recurrence, chunk k-2 (reads precomputed xp1)
//   blocks 172..235: gemm xp1 = W_ih1 @ h0 + b1, chunk k-1
// Tc=32, 16 chunks, 18 launches.

#define Tc 32
#define NCHUNK 16

// fp32 region (float offsets)
#define OFF_IH0   0        // REPACKED fp16: [8 pair][256 u][4 g][2] (32 KB)
#define OFF_B0    16384    // [256 u][4 g] = b_ih0+b_hh0
#define OFF_B1    17408    // [256 u][4 g] = b_ih1+b_hh1
#define OFF_C0S   18432    // [258][256] l0 cell state
#define OFF_C1S   84480    // [258][256] l1 cell state
#define OFF_H1S   150528   // [258][256] l1 h state
#define OFF_HLAST 216576   // [258][256]
#define FP_END    282624
// fp16 region (half offsets from h16 = (half*)(ws+FP_END))
#define H_HH0  0           // [128 p][256 u][4 g][2 k]
#define H_HH1  262144      // same layout
#define H_IH1  524288      // same layout (gemm streams it)
#define H_H0C  786432      // [2 slot][258 b][32 t][256 u]
#define H0SLOT 2113536
#define H_XP1  5013504     // [2 slot][258 b][32 t][1024 (u*4+g)]
#define XPSLOT 8454144
// end 21921792 halves; total ws ~= 45.0 MB (same as R6)

#define SMEM_BYTES 66560   // gemm needs 65536 (hc2); l0 ~49 KB; l1 ~17 KB

typedef _Float16 v2h __attribute__((ext_vector_type(2)));

__device__ __forceinline__ unsigned packh2(float a, float b) {
  __half2 h = __floats2half2_rn(a, b);
  return *(unsigned*)&h;
}
__device__ __forceinline__ float4 dot4(const float4 w, const v2h h, float4 acc) {
  const v2h* wg = (const v2h*)&w;
  acc.x = __builtin_amdgcn_fdot2(wg[0], h, acc.x, false);
  acc.y = __builtin_amdgcn_fdot2(wg[1], h, acc.y, false);
  acc.z = __builtin_amdgcn_fdot2(wg[2], h, acc.z, false);
  acc.w = __builtin_amdgcn_fdot2(wg[3], h, acc.w, false);
  return acc;
}
__device__ __forceinline__ float sigf(float x) {
  return __fdividef(1.f, 1.f + __expf(-x));
}
__device__ __forceinline__ float tanhf_fast(float x) {
  float ax = fabsf(x);
  float e = __expf(-2.f * ax);
  float t = __fdividef(1.f - e, 1.f + e);
  return copysignf(t, x);
}
__device__ __forceinline__ float h2f(unsigned short s) {
  __half h = __builtin_bit_cast(__half, s);
  return __half2float(h);
}
__device__ __forceinline__ float4 cvt4(ushort4 v) {
  float4 r;
  r.x = h2f(v.x); r.y = h2f(v.y); r.z = h2f(v.z); r.w = h2f(v.w);
  return r;
}
__device__ __forceinline__ v2h u2h(unsigned v) {
  return __builtin_bit_cast(v2h, v);
}

__global__ __launch_bounds__(256) void prep_kernel(
    const float* __restrict__ w_ih0, const float* __restrict__ w_hh0,
    const float* __restrict__ b_ih0, const float* __restrict__ b_hh0,
    const float* __restrict__ w_ih1, const float* __restrict__ w_hh1,
    const float* __restrict__ b_ih1, const float* __restrict__ b_hh1,
    float* __restrict__ ws) {
  const int idx = blockIdx.x * blockDim.x + threadIdx.x;  // [0,131072)
  const int g = idx & 3, u = (idx >> 2) & 255, p = idx >> 10;
  const int j = g * 256 + u;  // gate row in [0,1024)
  unsigned* h16u = (unsigned*)(ws + FP_END);
  h16u[H_HH0 / 2 + idx] = packh2(w_hh0[j * 256 + 2 * p], w_hh0[j * 256 + 2 * p + 1]);
  h16u[H_HH1 / 2 + idx] = packh2(w_hh1[j * 256 + 2 * p], w_hh1[j * 256 + 2 * p + 1]);
  h16u[H_IH1 / 2 + idx] = packh2(w_ih1[j * 256 + 2 * p], w_ih1[j * 256 + 2 * p + 1]);
  if (idx < 8192) {  // w_ih0 fp16: [p<8][u][g][2] in OFF_IH0 space
    ((unsigned*)(ws + OFF_IH0))[idx] =
        packh2(w_ih0[j * 16 + 2 * p], w_ih0[j * 16 + 2 * p + 1]);
  }
  if (idx < 1024) {
    ws[OFF_B0 + idx] = b_ih0[j] + b_hh0[j];
    ws[OFF_B1 + idx] = b_ih1[j] + b_hh1[j];
  }
}

__global__ __launch_bounds__(512, 2) void fused_kernel(
    float* __restrict__ ws, const float* __restrict__ x,
    const int* __restrict__ lengths, int step) {
  extern __shared__ __align__(16) char smem_raw[];
  const int bid = blockIdx.x;
  const int tid = threadIdx.x;
  __half* h16 = (__half*)(ws + FP_END);
  unsigned short* h0cS = (unsigned short*)(h16 + H_H0C);
  unsigned short* xpS = (unsigned short*)(h16 + H_XP1);

  if (bid < 86) {
    // ================= role: layer-0 recurrence, chunk kc = step ==========
    if (step >= NCHUNK) return;
    const int kc = step;
    const int kh = tid >> 8, u = tid & 255;
    const int bg = bid * 3;
    unsigned short* hb = (unsigned short*)smem_raw;      // [2][768]
    unsigned* xsp = (unsigned*)(smem_raw + 4096);        // [2][3][8] x pairs
    float* scratch = (float*)(smem_raw + 4352);          // 256*13 floats
    float4* wxl = (float4*)(smem_raw + 18048);           // [8 p][256 u] 32 KB

    int len[3];
    #pragma unroll
    for (int b = 0; b < 3; ++b) len[b] = (bg + b < 256) ? lengths[bg + b] : 1;
    const int tmaxb = max(len[0], max(len[1], len[2]));
    if (kc * Tc >= tmaxb) return;
    const int tend = min(Tc, tmaxb - kc * Tc);
    const int slot = kc & 1, slotP = slot ^ 1;

    // stage w_ih0 fp16 into LDS (once per launch)
    {
      const float4* gwx = (const float4*)(ws + OFF_IH0);
      #pragma unroll
      for (int e = 0; e < 4; ++e) wxl[tid + e * 512] = gwx[tid + e * 512];
    }

    // register-resident half of w_hh0: pairs kh*64 .. kh*64+31
    const float4* wqR = (const float4*)(h16 + H_HH0) + (size_t)(kh * 64) * 256 + u;
    float4 wreg[32];
    #pragma unroll
    for (int p = 0; p < 32; ++p) wreg[p] = wqR[p * 256];
    const float4* wqS = wqR + 32 * 256;  // streamed pairs 32..63
    const float4 bias = ((const float4*)(ws + OFF_B0))[u];

    float c[3] = {0.f, 0.f, 0.f};
    if (kh == 0) {
      #pragma unroll
      for (int b = 0; b < 3; ++b) {
        unsigned short hv = 0;
        if (kc > 0) {
          hv = h0cS[(size_t)slotP * H0SLOT + ((size_t)(bg + b) * 32 + 31) * 256 + u];
          c[b] = ws[OFF_C0S + (bg + b) * 256 + u];
        }
        hb[0 * 768 + b * 256 + u] = hv;
      }
    }
    if (tid < 24) {  // stage x pairs for t0
      int b = tid >> 3, i = tid & 7;
      int bb = min(bg + b, 255);
      const float* xp = x + (size_t)bb * 8192 + (kc * Tc) * 16;
      xsp[0 * 24 + b * 8 + i] = packh2(xp[2 * i], xp[2 * i + 1]);
    }
    __syncthreads();

    for (int tc = 0; tc < tend; ++tc) {
      const int cur = tc & 1, nxt = cur ^ 1;
      float4 A0, A1, A2;
      if (kh == 0) { A0 = bias; A1 = bias; A2 = bias; }
      else { A0 = make_float4(0, 0, 0, 0); A1 = A0; A2 = A0; }

      // x-part: 4 k-pairs per half from LDS weights
      #pragma unroll
      for (int p = 0; p < 4; ++p) {
        float4 w = wxl[(kh * 4 + p) * 256 + u];
        v2h x0 = u2h(xsp[cur * 24 + 0 * 8 + kh * 4 + p]);
        v2h x1 = u2h(xsp[cur * 24 + 1 * 8 + kh * 4 + p]);
        v2h x2 = u2h(xsp[cur * 24 + 2 * 8 + kh * 4 + p]);
        A0 = dot4(w, x0, A0);
        A1 = dot4(w, x1, A1);
        A2 = dot4(w, x2, A2);
      }

      const float4* h0r0 = (const float4*)(hb + cur * 768 + 0 * 256 + kh * 128);
      const float4* h0r1 = (const float4*)(hb + cur * 768 + 1 * 256 + kh * 128);
      const float4* h0r2 = (const float4*)(hb + cur * 768 + 2 * 256 + kh * 128);

      // h-part A: register-resident pairs 0..31 (h groups 0..7)
      #pragma unroll
      for (int grp = 0; grp < 8; ++grp) {
        float4 h40 = h0r0[grp], h41 = h0r1[grp], h42 = h0r2[grp];
        const v2h* hp0 = (const v2h*)&h40;
        const v2h* hp1 = (const v2h*)&h41;
        const v2h* hp2 = (const v2h*)&h42;
        #pragma unroll
        for (int q = 0; q < 4; ++q) {
          A0 = dot4(wreg[grp * 4 + q], hp0[q], A0);
          A1 = dot4(wreg[grp * 4 + q], hp1[q], A1);
          A2 = dot4(wreg[grp * 4 + q], hp2[q], A2);
        }
      }
      // h-part B: streamed pairs 32..63 (h groups 8..15), 3-buf 2-deep
      {
        float4 B[3][4];
        #pragma unroll
        for (int p = 0; p < 4; ++p) {
          B[0][p] = wqS[p * 256];
          B[1][p] = wqS[(4 + p) * 256];
        }
        #pragma unroll
        for (int g = 0; g < 8; ++g) {
          if (g + 2 < 8) {
            #pragma unroll
            for (int p = 0; p < 4; ++p)
              B[(g + 2) % 3][p] = wqS[((g + 2) * 4 + p) * 256];
          }
          const float4* wbuf = B[g % 3];
          float4 h40 = h0r0[8 + g], h41 = h0r1[8 + g], h42 = h0r2[8 + g];
          const v2h* hp0 = (const v2h*)&h40;
          const v2h* hp1 = (const v2h*)&h41;
          const v2h* hp2 = (const v2h*)&h42;
          #pragma unroll
          for (int q = 0; q < 4; ++q) {
            A0 = dot4(wbuf[q], hp0[q], A0);
            A1 = dot4(wbuf[q], hp1[q], A1);
            A2 = dot4(wbuf[q], hp2[q], A2);
          }
        }
      }

      if (kh == 1) {
        #pragma unroll
        for (int g = 0; g < 4; ++g) {
          scratch[u * 13 + g] = ((const float*)&A0)[g];
          scratch[u * 13 + 4 + g] = ((const float*)&A1)[g];
          scratch[u * 13 + 8 + g] = ((const float*)&A2)[g];
        }
        if (tid < 256 + 24) {  // stage x pairs for t+1
          int bi = tid - 256, b = bi >> 3, i = bi & 7;
          int bb = min(bg + b, 255);
          int tn = min(kc * Tc + tc + 1, 511);
          const float* xp = x + (size_t)bb * 8192 + tn * 16;
          xsp[nxt * 24 + b * 8 + i] = packh2(xp[2 * i], xp[2 * i + 1]);
        }
      }
      __syncthreads();
      if (kh == 0) {
        float4 B0, B1, B2;
        #pragma unroll
        for (int g = 0; g < 4; ++g) {
          ((float*)&B0)[g] = scratch[u * 13 + g];
          ((float*)&B1)[g] = scratch[u * 13 + 4 + g];
          ((float*)&B2)[g] = scratch[u * 13 + 8 + g];
        }
        A0.x += B0.x; A0.y += B0.y; A0.z += B0.z; A0.w += B0.w;
        A1.x += B1.x; A1.y += B1.y; A1.z += B1.z; A1.w += B1.w;
        A2.x += B2.x; A2.y += B2.y; A2.z += B2.z; A2.w += B2.w;
        float4 A[3] = {A0, A1, A2};
        #pragma unroll
        for (int b = 0; b < 3; ++b) {
          float ig = sigf(A[b].x), fg = sigf(A[b].y);
          float gg = tanhf_fast(A[b].z), og = sigf(A[b].w);
          c[b] = fg * c[b] + ig * gg;
          float h = og * tanhf_fast(c[b]);
          unsigned short hu = __half_as_ushort(__float2half(h));
          hb[nxt * 768 + b * 256 + u] = hu;
          h0cS[(size_t)slot * H0SLOT + ((size_t)(bg + b) * 32 + tc) * 256 + u] = hu;
        }
      }
      __syncthreads();
    }
    if (kh == 0) {
      #pragma unroll
      for (int b = 0; b < 3; ++b) ws[OFF_C0S + (bg + b) * 256 + u] = c[b];
    }

  } else if (bid < 172) {
    // ============ role: layer-1 recurrence, chunk kc = step-2 =============
    if (step < 2 || step >= NCHUNK + 2) return;
    const int kc = step - 2;
    const int kh = tid >> 8, u = tid & 255;
    const int bg = (bid - 86) * 3;
    unsigned short* h1b = (unsigned short*)smem_raw;  // [2][768]
    float* scratch = (float*)(smem_raw + 4096);       // 256*13

    int len[3];
    #pragma unroll
    for (int b = 0; b < 3; ++b) len[b] = (bg + b < 256) ? lengths[bg + b] : 1;
    const int tmaxb = max(len[0], max(len[1], len[2]));
    if (kc * Tc >= tmaxb) return;
    const int tend = min(Tc, tmaxb - kc * Tc);
    const int slot = kc & 1;

    const float4* wqR = (const float4*)(h16 + H_HH1) + (size_t)(kh * 64) * 256 + u;
    float4 wreg[32];
    #pragma unroll
    for (int p = 0; p < 32; ++p) wreg[p] = wqR[p * 256];
    const float4* wqS = wqR + 32 * 256;

    float c[3] = {0.f, 0.f, 0.f}, hout[3] = {0.f, 0.f, 0.f};
    if (kh == 0) {
      #pragma unroll
      for (int b = 0; b < 3; ++b) {
        float hv = 0.f;
        if (kc > 0) {
          hv = ws[OFF_H1S + (bg + b) * 256 + u];
          c[b] = ws[OFF_C1S + (bg + b) * 256 + u];
        }
        h1b[0 * 768 + b * 256 + u] = __half_as_ushort(__float2half(hv));
      }
    }
    const unsigned short* xb =
        xpS + (size_t)slot * XPSLOT + (size_t)bg * 32768 + u * 4;
    ushort4 xc0, xc1, xc2;
    if (kh == 0) {
      xc0 = *(const ushort4*)(xb);
      xc1 = *(const ushort4*)(xb + 32768);
      xc2 = *(const ushort4*)(xb + 65536);
    }
    __syncthreads();

    for (int tc = 0; tc < tend; ++tc) {
      const int cur = tc & 1, nxt = cur ^ 1;
      float4 A0, A1, A2;
      ushort4 xn0, xn1, xn2;
      if (kh == 0) {
        A0 = cvt4(xc0); A1 = cvt4(xc1); A2 = cvt4(xc2);  // xp1 (bias folded)
        if (tc + 1 < tend) {
          xn0 = *(const ushort4*)(xb + (tc + 1) * 1024);
          xn1 = *(const ushort4*)(xb + 32768 + (tc + 1) * 1024);
          xn2 = *(const ushort4*)(xb + 65536 + (tc + 1) * 1024);
        }
      } else { A0 = make_float4(0, 0, 0, 0); A1 = A0; A2 = A0; }

      const float4* r0 = (const float4*)(h1b + cur * 768 + 0 * 256 + kh * 128);
      const float4* r1 = (const float4*)(h1b + cur * 768 + 1 * 256 + kh * 128);
      const float4* r2 = (const float4*)(h1b + cur * 768 + 2 * 256 + kh * 128);

      // register-resident pairs 0..31
      #pragma unroll
      for (int grp = 0; grp < 8; ++grp) {
        float4 h40 = r0[grp], h41 = r1[grp], h42 = r2[grp];
        const v2h* hp0 = (const v2h*)&h40;
        const v2h* hp1 = (const v2h*)&h41;
        const v2h* hp2 = (const v2h*)&h42;
        #pragma unroll
        for (int q = 0; q < 4; ++q) {
          A0 = dot4(wreg[grp * 4 + q], hp0[q], A0);
          A1 = dot4(wreg[grp * 4 + q], hp1[q], A1);
          A2 = dot4(wreg[grp * 4 + q], hp2[q], A2);
        }
      }
      // streamed pairs 32..63
      {
        float4 B[3][4];
        #pragma unroll
        for (int p = 0; p < 4; ++p) {
          B[0][p] = wqS[p * 256];
          B[1][p] = wqS[(4 + p) * 256];
        }
        #pragma unroll
        for (int g = 0; g < 8; ++g) {
          if (g + 2 < 8) {
            #pragma unroll
            for (int p = 0; p < 4; ++p)
              B[(g + 2) % 3][p] = wqS[((g + 2) * 4 + p) * 256];
          }
          const float4* wbuf = B[g % 3];
          float4 h40 = r0[8 + g], h41 = r1[8 + g], h42 = r2[8 + g];
          const v2h* hp0 = (const v2h*)&h40;
          const v2h* hp1 = (const v2h*)&h41;
          const v2h* hp2 = (const v2h*)&h42;
          #pragma unroll
          for (int q = 0; q < 4; ++q) {
            A0 = dot4(wbuf[q], hp0[q], A0);
            A1 = dot4(wbuf[q], hp1[q], A1);
            A2 = dot4(wbuf[q], hp2[q], A2);
          }
        }
      }

      if (kh == 1) {
        #pragma unroll
        for (int g = 0; g < 4; ++g) {
          scratch[u * 13 + g] = ((const float*)&A0)[g];
          scratch[u * 13 + 4 + g] = ((const float*)&A1)[g];
          scratch[u * 13 + 8 + g] = ((const float*)&A2)[g];
        }
      }
      __syncthreads();
      if (kh == 0) {
        float4 B0, B1, B2;
        #pragma unroll
        for (int g = 0; g < 4; ++g) {
          ((float*)&B0)[g] = scratch[u * 13 + g];
          ((float*)&B1)[g] = scratch[u * 13 + 4 + g];
          ((float*)&B2)[g] = scratch[u * 13 + 8 + g];
        }
        A0.x += B0.x; A0.y += B0.y; A0.z += B0.z; A0.w += B0.w;
        A1.x += B1.x; A1.y += B1.y; A1.z += B1.z; A1.w += B1.w;
        A2.x += B2.x; A2.y += B2.y; A2.z += B2.z; A2.w += B2.w;
        float4 A[3] = {A0, A1, A2};
        const int t = kc * Tc + tc;
        #pragma unroll
        for (int b = 0; b < 3; ++b) {
          float ig = sigf(A[b].x), fg = sigf(A[b].y);
          float gg = tanhf_fast(A[b].z), og = sigf(A[b].w);
          c[b] = fg * c[b] + ig * gg;
          float h = og * tanhf_fast(c[b]);
          hout[b] = h;
          h1b[nxt * 768 + b * 256 + u] = __half_as_ushort(__float2half(h));
          if (t == len[b] - 1) ws[OFF_HLAST + (bg + b) * 256 + u] = h;
        }
        xc0 = xn0; xc1 = xn1; xc2 = xn2;
      }
      __syncthreads();
    }
    if (kh == 0) {
      #pragma unroll
      for (int b = 0; b < 3; ++b) {
        ws[OFF_C1S + (bg + b) * 256 + u] = c[b];
        ws[OFF_H1S + (bg + b) * 256 + u] = hout[b];
      }
    }

  } else {
    // ===== role: gemm xp1 = W_ih1 @ h0 + b1, chunk kc = step-1 ============
    if (step < 1 || step >= NCHUNK + 1) return;
    if (bid >= 236) return;
    const int kc = step - 1;
    const int gid = bid - 172;  // [0,64)
    const int b0g = gid * 4;    // 4 batches per block
    const int rt = tid & 63, wv = tid >> 6;
    __half2* hc2 = (__half2*)smem_raw;  // [128 p][128 col]

    int lmax = 0;
    #pragma unroll
    for (int i = 0; i < 4; ++i) lmax = max(lmax, lengths[b0g + i]);
    if (kc * Tc >= lmax) return;
    const int slot = kc & 1;

    {
      const unsigned short* src =
          h0cS + (size_t)slot * H0SLOT + (size_t)b0g * 8192;
      const int cl = tid & 127, pg = tid >> 7;
      #pragma unroll
      for (int pp = 0; pp < 32; pp += 4) {
        const int p0 = pg * 32 + pp;
        uint4 v = *(const uint4*)(src + (size_t)cl * 256 + p0 * 2);
        unsigned* d = (unsigned*)hc2;
        d[(p0 + 0) * 128 + cl] = v.x;
        d[(p0 + 1) * 128 + cl] = v.y;
        d[(p0 + 2) * 128 + cl] = v.z;
        d[(p0 + 3) * 128 + cl] = v.w;
      }
    }
    __syncthreads();

    const __half* Wb = h16 + H_IH1;  // [p][u][g][2]
    unsigned short* xdst = xpS + (size_t)slot * XPSLOT;
    #pragma unroll 1
    for (int rp = 0; rp < 2; ++rp) {
      #pragma unroll 1
      for (int cp = 0; cp < 2; ++cp) {
        const int uA = rp * 128 + rt, uB = uA + 64;
        const int c0 = cp * 64 + wv * 8;
        const float4 bA = ((const float4*)(ws + OFF_B1))[uA];
        const float4 bB = ((const float4*)(ws + OFF_B1))[uB];
        float accA[4][8], accB[4][8];
        #pragma unroll
        for (int g = 0; g < 4; ++g)
          #pragma unroll
          for (int cc = 0; cc < 8; ++cc) {
            accA[g][cc] = ((const float*)&bA)[g];
            accB[g][cc] = ((const float*)&bB)[g];
          }
        #pragma unroll 2
        for (int p = 0; p < 128; ++p) {
          float4 wA = *(const float4*)(Wb + (size_t)p * 2048 + uA * 8);
          float4 wB = *(const float4*)(Wb + (size_t)p * 2048 + uB * 8);
          float4 h0v = *(const float4*)(hc2 + p * 128 + c0);
          float4 h1v = *(const float4*)(hc2 + p * 128 + c0 + 4);
          const v2h* ga = (const v2h*)&wA;
          const v2h* gb = (const v2h*)&wB;
          const v2h* hv = (const v2h*)&h0v;
          const v2h* hw = (const v2h*)&h1v;
          #pragma unroll
          for (int g = 0; g < 4; ++g) {
            #pragma unroll
            for (int cc = 0; cc < 4; ++cc) {
              accA[g][cc] = __builtin_amdgcn_fdot2(ga[g], hv[cc], accA[g][cc], false);
              accA[g][cc + 4] = __builtin_amdgcn_fdot2(ga[g], hw[cc], accA[g][cc + 4], false);
              accB[g][cc] = __builtin_amdgcn_fdot2(gb[g], hv[cc], accB[g][cc], false);
              accB[g][cc + 4] = __builtin_amdgcn_fdot2(gb[g], hw[cc], accB[g][cc + 4], false);
            }
          }
        }
        #pragma unroll
        for (int cc = 0; cc < 8; ++cc) {
          const int col = c0 + cc;
          const size_t cb = ((size_t)(b0g + (col >> 5)) * 32 + (col & 31)) * 1024;
          ushort4 oA, oB;
          oA.x = __half_as_ushort(__float2half(accA[0][cc]));
          oA.y = __half_as_ushort(__float2half(accA[1][cc]));
          oA.z = __half_as_ushort(__float2half(accA[2][cc]));
          oA.w = __half_as_ushort(__float2half(accA[3][cc]));
          oB.x = __half_as_ushort(__float2half(accB[0][cc]));
          oB.y = __half_as_ushort(__float2half(accB[1][cc]));
          oB.z = __half_as_ushort(__float2half(accB[2][cc]));
          oB.w = __half_as_ushort(__float2half(accB[3][cc]));
          *(ushort4*)(xdst + cb + uA * 4) = oA;
          *(ushort4*)(xdst + cb + uB * 4) = oB;
        }
      }
    }
  }
}

__global__ __launch_bounds__(256) void fc_kernel(
    const float* __restrict__ ws, const float* __restrict__ fc_w,
    const float* __restrict__ fc_b, float* __restrict__ out) {
  __shared__ float red[256];
  const int tid = threadIdx.x;
  const int b = blockIdx.x;
  red[tid] = fmaxf(ws[OFF_HLAST + b * 256 + tid], 0.f) * fc_w[tid];
  __syncthreads();
  #pragma unroll
  for (int s = 128; s > 0; s >>= 1) {
    if (tid < s) red[tid] += red[tid + s];
    __syncthreads();
  }
  if (tid == 0) out[b] = red[0] + fc_b[0];
}

extern "C" void kernel_launch(void* const* d_in, const int* in_sizes, int n_in,
                              void* d_out, int out_size, void* d_ws, size_t ws_size,
                              hipStream_t stream) {
  const float* x     = (const float*)d_in[0];
  const int*   lens  = (const int*)d_in[1];
  const float* w_ih0 = (const float*)d_in[2];
  const float* w_hh0 = (const float*)d_in[3];
  const float* b_ih0 = (const float*)d_in[4];
  const float* b_hh0 = (const float*)d_in[5];
  const float* w_ih1 = (const float*)d_in[6];
  const float* w_hh1 = (const float*)d_in[7];
  const float* b_ih1 = (const float*)d_in[8];
  const float* b_hh1 = (const float*)d_in[9];
  const float* fc_w  = (const float*)d_in[10];
  const float* fc_b  = (const float*)d_in[11];
  float* out = (float*)d_out;
  float* ws  = (float*)d_ws;

  hipLaunchKernelGGL(prep_kernel, dim3(512), dim3(256), 0, stream,
                     w_ih0, w_hh0, b_ih0, b_hh0, w_ih1, w_hh1, b_ih1, b_hh1, ws);
  hipFuncSetAttribute(reinterpret_cast<const void*>(fused_kernel),
                      hipFuncAttributeMaxDynamicSharedMemorySize, SMEM_BYTES);
  for (int k = 0; k < NCHUNK + 2; ++k) {
    hipLaunchKernelGGL(fused_kernel, dim3(236), dim3(512), SMEM_BYTES, stream,
                       ws, x, lens, k);
  }
  hipLaunchKernelGGL(fc_kernel, dim3(256), dim3(256), 0, stream,
                     ws, fc_w, fc_b, out);
}

// Round 8
// 3096.669 us; speedup vs baseline: 1.0158x; 1.0158x over previous
//
#include <hip/hip_runtime.h>
#include <hip/hip_fp16.h>

// B=256, T=512, F=16, H=256, L=2 LSTM + gather(len-1) + ReLU + FC(256->1).
//
// R8: R7 + amdgpu_waves_per_eu(2,2) on fused_kernel. R7's register-resident
// weight half was silently spilled (VGPR_Count stayed 128: the backend's
// default occupancy target is 4 waves/EU). Forcing max=2 waves/EU raises the
// allocator's budget to 256 VGPRs so wreg[32] (128 VGPR) stays live, halving
// the per-block recurrent-weight stream to 256 KB/step (the per-CU L2 wall).
//   blocks   0..85 : l0 recurrence, chunk k
//   blocks  86..171: l1 recurrence, chunk k-2 (reads precomputed xp1)
//   blocks 172..235: gemm xp1 = W_ih1 @ h0 + b1, chunk k-1
// Tc=32, 16 chunks, 18 launches.

#define Tc 32
#define NCHUNK 16

// fp32 region (float offsets)
#define OFF_IH0   0        // REPACKED fp16: [8 pair][256 u][4 g][2] (32 KB)
#define OFF_B0    16384    // [256 u][4 g] = b_ih0+b_hh0
#define OFF_B1    17408    // [256 u][4 g] = b_ih1+b_hh1
#define OFF_C0S   18432    // [258][256] l0 cell state
#define OFF_C1S   84480    // [258][256] l1 cell state
#define OFF_H1S   150528   // [258][256] l1 h state
#define OFF_HLAST 216576   // [258][256]
#define FP_END    282624
// fp16 region (half offsets from h16 = (half*)(ws+FP_END))
#define H_HH0  0           // [128 p][256 u][4 g][2 k]
#define H_HH1  262144      // same layout
#define H_IH1  524288      // same layout (gemm streams it)
#define H_H0C  786432      // [2 slot][258 b][32 t][256 u]
#define H0SLOT 2113536
#define H_XP1  5013504     // [2 slot][258 b][32 t][1024 (u*4+g)]
#define XPSLOT 8454144
// end 21921792 halves; total ws ~= 45.0 MB

#define SMEM_BYTES 66560   // gemm needs 65536 (hc2); l0 ~49 KB; l1 ~17 KB

typedef _Float16 v2h __attribute__((ext_vector_type(2)));

__device__ __forceinline__ unsigned packh2(float a, float b) {
  __half2 h = __floats2half2_rn(a, b);
  return *(unsigned*)&h;
}
__device__ __forceinline__ float4 dot4(const float4 w, const v2h h, float4 acc) {
  const v2h* wg = (const v2h*)&w;
  acc.x = __builtin_amdgcn_fdot2(wg[0], h, acc.x, false);
  acc.y = __builtin_amdgcn_fdot2(wg[1], h, acc.y, false);
  acc.z = __builtin_amdgcn_fdot2(wg[2], h, acc.z, false);
  acc.w = __builtin_amdgcn_fdot2(wg[3], h, acc.w, false);
  return acc;
}
__device__ __forceinline__ float sigf(float x) {
  return __fdividef(1.f, 1.f + __expf(-x));
}
__device__ __forceinline__ float tanhf_fast(float x) {
  float ax = fabsf(x);
  float e = __expf(-2.f * ax);
  float t = __fdividef(1.f - e, 1.f + e);
  return copysignf(t, x);
}
__device__ __forceinline__ float h2f(unsigned short s) {
  __half h = __builtin_bit_cast(__half, s);
  return __half2float(h);
}
__device__ __forceinline__ float4 cvt4(ushort4 v) {
  float4 r;
  r.x = h2f(v.x); r.y = h2f(v.y); r.z = h2f(v.z); r.w = h2f(v.w);
  return r;
}
__device__ __forceinline__ v2h u2h(unsigned v) {
  return __builtin_bit_cast(v2h, v);
}

__global__ __launch_bounds__(256) void prep_kernel(
    const float* __restrict__ w_ih0, const float* __restrict__ w_hh0,
    const float* __restrict__ b_ih0, const float* __restrict__ b_hh0,
    const float* __restrict__ w_ih1, const float* __restrict__ w_hh1,
    const float* __restrict__ b_ih1, const float* __restrict__ b_hh1,
    float* __restrict__ ws) {
  const int idx = blockIdx.x * blockDim.x + threadIdx.x;  // [0,131072)
  const int g = idx & 3, u = (idx >> 2) & 255, p = idx >> 10;
  const int j = g * 256 + u;  // gate row in [0,1024)
  unsigned* h16u = (unsigned*)(ws + FP_END);
  h16u[H_HH0 / 2 + idx] = packh2(w_hh0[j * 256 + 2 * p], w_hh0[j * 256 + 2 * p + 1]);
  h16u[H_HH1 / 2 + idx] = packh2(w_hh1[j * 256 + 2 * p], w_hh1[j * 256 + 2 * p + 1]);
  h16u[H_IH1 / 2 + idx] = packh2(w_ih1[j * 256 + 2 * p], w_ih1[j * 256 + 2 * p + 1]);
  if (idx < 8192) {  // w_ih0 fp16: [p<8][u][g][2] in OFF_IH0 space
    ((unsigned*)(ws + OFF_IH0))[idx] =
        packh2(w_ih0[j * 16 + 2 * p], w_ih0[j * 16 + 2 * p + 1]);
  }
  if (idx < 1024) {
    ws[OFF_B0 + idx] = b_ih0[j] + b_hh0[j];
    ws[OFF_B1 + idx] = b_ih1[j] + b_hh1[j];
  }
}

__global__ __launch_bounds__(512)
__attribute__((amdgpu_waves_per_eu(2, 2)))
void fused_kernel(
    float* __restrict__ ws, const float* __restrict__ x,
    const int* __restrict__ lengths, int step) {
  extern __shared__ __align__(16) char smem_raw[];
  const int bid = blockIdx.x;
  const int tid = threadIdx.x;
  __half* h16 = (__half*)(ws + FP_END);
  unsigned short* h0cS = (unsigned short*)(h16 + H_H0C);
  unsigned short* xpS = (unsigned short*)(h16 + H_XP1);

  if (bid < 86) {
    // ================= role: layer-0 recurrence, chunk kc = step ==========
    if (step >= NCHUNK) return;
    const int kc = step;
    const int kh = tid >> 8, u = tid & 255;
    const int bg = bid * 3;
    unsigned short* hb = (unsigned short*)smem_raw;      // [2][768]
    unsigned* xsp = (unsigned*)(smem_raw + 4096);        // [2][3][8] x pairs
    float* scratch = (float*)(smem_raw + 4352);          // 256*13 floats
    float4* wxl = (float4*)(smem_raw + 18048);           // [8 p][256 u] 32 KB

    int len[3];
    #pragma unroll
    for (int b = 0; b < 3; ++b) len[b] = (bg + b < 256) ? lengths[bg + b] : 1;
    const int tmaxb = max(len[0], max(len[1], len[2]));
    if (kc * Tc >= tmaxb) return;
    const int tend = min(Tc, tmaxb - kc * Tc);
    const int slot = kc & 1, slotP = slot ^ 1;

    // stage w_ih0 fp16 into LDS (once per launch)
    {
      const float4* gwx = (const float4*)(ws + OFF_IH0);
      #pragma unroll
      for (int e = 0; e < 4; ++e) wxl[tid + e * 512] = gwx[tid + e * 512];
    }

    // register-resident half of w_hh0: pairs kh*64 .. kh*64+31
    const float4* wqR = (const float4*)(h16 + H_HH0) + (size_t)(kh * 64) * 256 + u;
    float4 wreg[32];
    #pragma unroll
    for (int p = 0; p < 32; ++p) wreg[p] = wqR[p * 256];
    const float4* wqS = wqR + 32 * 256;  // streamed pairs 32..63
    const float4 bias = ((const float4*)(ws + OFF_B0))[u];

    float c[3] = {0.f, 0.f, 0.f};
    if (kh == 0) {
      #pragma unroll
      for (int b = 0; b < 3; ++b) {
        unsigned short hv = 0;
        if (kc > 0) {
          hv = h0cS[(size_t)slotP * H0SLOT + ((size_t)(bg + b) * 32 + 31) * 256 + u];
          c[b] = ws[OFF_C0S + (bg + b) * 256 + u];
        }
        hb[0 * 768 + b * 256 + u] = hv;
      }
    }
    if (tid < 24) {  // stage x pairs for t0
      int b = tid >> 3, i = tid & 7;
      int bb = min(bg + b, 255);
      const float* xp = x + (size_t)bb * 8192 + (kc * Tc) * 16;
      xsp[0 * 24 + b * 8 + i] = packh2(xp[2 * i], xp[2 * i + 1]);
    }
    __syncthreads();

    for (int tc = 0; tc < tend; ++tc) {
      const int cur = tc & 1, nxt = cur ^ 1;
      float4 A0, A1, A2;
      if (kh == 0) { A0 = bias; A1 = bias; A2 = bias; }
      else { A0 = make_float4(0, 0, 0, 0); A1 = A0; A2 = A0; }

      // x-part: 4 k-pairs per half from LDS weights
      #pragma unroll
      for (int p = 0; p < 4; ++p) {
        float4 w = wxl[(kh * 4 + p) * 256 + u];
        v2h x0 = u2h(xsp[cur * 24 + 0 * 8 + kh * 4 + p]);
        v2h x1 = u2h(xsp[cur * 24 + 1 * 8 + kh * 4 + p]);
        v2h x2 = u2h(xsp[cur * 24 + 2 * 8 + kh * 4 + p]);
        A0 = dot4(w, x0, A0);
        A1 = dot4(w, x1, A1);
        A2 = dot4(w, x2, A2);
      }

      const float4* h0r0 = (const float4*)(hb + cur * 768 + 0 * 256 + kh * 128);
      const float4* h0r1 = (const float4*)(hb + cur * 768 + 1 * 256 + kh * 128);
      const float4* h0r2 = (const float4*)(hb + cur * 768 + 2 * 256 + kh * 128);

      // h-part A: register-resident pairs 0..31 (h groups 0..7)
      #pragma unroll
      for (int grp = 0; grp < 8; ++grp) {
        float4 h40 = h0r0[grp], h41 = h0r1[grp], h42 = h0r2[grp];
        const v2h* hp0 = (const v2h*)&h40;
        const v2h* hp1 = (const v2h*)&h41;
        const v2h* hp2 = (const v2h*)&h42;
        #pragma unroll
        for (int q = 0; q < 4; ++q) {
          A0 = dot4(wreg[grp * 4 + q], hp0[q], A0);
          A1 = dot4(wreg[grp * 4 + q], hp1[q], A1);
          A2 = dot4(wreg[grp * 4 + q], hp2[q], A2);
        }
      }
      // h-part B: streamed pairs 32..63 (h groups 8..15), 3-buf 2-deep
      {
        float4 B[3][4];
        #pragma unroll
        for (int p = 0; p < 4; ++p) {
          B[0][p] = wqS[p * 256];
          B[1][p] = wqS[(4 + p) * 256];
        }
        #pragma unroll
        for (int g = 0; g < 8; ++g) {
          if (g + 2 < 8) {
            #pragma unroll
            for (int p = 0; p < 4; ++p)
              B[(g + 2) % 3][p] = wqS[((g + 2) * 4 + p) * 256];
          }
          const float4* wbuf = B[g % 3];
          float4 h40 = h0r0[8 + g], h41 = h0r1[8 + g], h42 = h0r2[8 + g];
          const v2h* hp0 = (const v2h*)&h40;
          const v2h* hp1 = (const v2h*)&h41;
          const v2h* hp2 = (const v2h*)&h42;
          #pragma unroll
          for (int q = 0; q < 4; ++q) {
            A0 = dot4(wbuf[q], hp0[q], A0);
            A1 = dot4(wbuf[q], hp1[q], A1);
            A2 = dot4(wbuf[q], hp2[q], A2);
          }
        }
      }

      if (kh == 1) {
        #pragma unroll
        for (int g = 0; g < 4; ++g) {
          scratch[u * 13 + g] = ((const float*)&A0)[g];
          scratch[u * 13 + 4 + g] = ((const float*)&A1)[g];
          scratch[u * 13 + 8 + g] = ((const float*)&A2)[g];
        }
        if (tid < 256 + 24) {  // stage x pairs for t+1
          int bi = tid - 256, b = bi >> 3, i = bi & 7;
          int bb = min(bg + b, 255);
          int tn = min(kc * Tc + tc + 1, 511);
          const float* xp = x + (size_t)bb * 8192 + tn * 16;
          xsp[nxt * 24 + b * 8 + i] = packh2(xp[2 * i], xp[2 * i + 1]);
        }
      }
      __syncthreads();
      if (kh == 0) {
        float4 B0, B1, B2;
        #pragma unroll
        for (int g = 0; g < 4; ++g) {
          ((float*)&B0)[g] = scratch[u * 13 + g];
          ((float*)&B1)[g] = scratch[u * 13 + 4 + g];
          ((float*)&B2)[g] = scratch[u * 13 + 8 + g];
        }
        A0.x += B0.x; A0.y += B0.y; A0.z += B0.z; A0.w += B0.w;
        A1.x += B1.x; A1.y += B1.y; A1.z += B1.z; A1.w += B1.w;
        A2.x += B2.x; A2.y += B2.y; A2.z += B2.z; A2.w += B2.w;
        float4 A[3] = {A0, A1, A2};
        #pragma unroll
        for (int b = 0; b < 3; ++b) {
          float ig = sigf(A[b].x), fg = sigf(A[b].y);
          float gg = tanhf_fast(A[b].z), og = sigf(A[b].w);
          c[b] = fg * c[b] + ig * gg;
          float h = og * tanhf_fast(c[b]);
          unsigned short hu = __half_as_ushort(__float2half(h));
          hb[nxt * 768 + b * 256 + u] = hu;
          h0cS[(size_t)slot * H0SLOT + ((size_t)(bg + b) * 32 + tc) * 256 + u] = hu;
        }
      }
      __syncthreads();
    }
    if (kh == 0) {
      #pragma unroll
      for (int b = 0; b < 3; ++b) ws[OFF_C0S + (bg + b) * 256 + u] = c[b];
    }

  } else if (bid < 172) {
    // ============ role: layer-1 recurrence, chunk kc = step-2 =============
    if (step < 2 || step >= NCHUNK + 2) return;
    const int kc = step - 2;
    const int kh = tid >> 8, u = tid & 255;
    const int bg = (bid - 86) * 3;
    unsigned short* h1b = (unsigned short*)smem_raw;  // [2][768]
    float* scratch = (float*)(smem_raw + 4096);       // 256*13

    int len[3];
    #pragma unroll
    for (int b = 0; b < 3; ++b) len[b] = (bg + b < 256) ? lengths[bg + b] : 1;
    const int tmaxb = max(len[0], max(len[1], len[2]));
    if (kc * Tc >= tmaxb) return;
    const int tend = min(Tc, tmaxb - kc * Tc);
    const int slot = kc & 1;

    const float4* wqR = (const float4*)(h16 + H_HH1) + (size_t)(kh * 64) * 256 + u;
    float4 wreg[32];
    #pragma unroll
    for (int p = 0; p < 32; ++p) wreg[p] = wqR[p * 256];
    const float4* wqS = wqR + 32 * 256;

    float c[3] = {0.f, 0.f, 0.f}, hout[3] = {0.f, 0.f, 0.f};
    if (kh == 0) {
      #pragma unroll
      for (int b = 0; b < 3; ++b) {
        float hv = 0.f;
        if (kc > 0) {
          hv = ws[OFF_H1S + (bg + b) * 256 + u];
          c[b] = ws[OFF_C1S + (bg + b) * 256 + u];
        }
        h1b[0 * 768 + b * 256 + u] = __half_as_ushort(__float2half(hv));
      }
    }
    const unsigned short* xb =
        xpS + (size_t)slot * XPSLOT + (size_t)bg * 32768 + u * 4;
    ushort4 xc0, xc1, xc2;
    if (kh == 0) {
      xc0 = *(const ushort4*)(xb);
      xc1 = *(const ushort4*)(xb + 32768);
      xc2 = *(const ushort4*)(xb + 65536);
    }
    __syncthreads();

    for (int tc = 0; tc < tend; ++tc) {
      const int cur = tc & 1, nxt = cur ^ 1;
      float4 A0, A1, A2;
      ushort4 xn0, xn1, xn2;
      if (kh == 0) {
        A0 = cvt4(xc0); A1 = cvt4(xc1); A2 = cvt4(xc2);  // xp1 (bias folded)
        if (tc + 1 < tend) {
          xn0 = *(const ushort4*)(xb + (tc + 1) * 1024);
          xn1 = *(const ushort4*)(xb + 32768 + (tc + 1) * 1024);
          xn2 = *(const ushort4*)(xb + 65536 + (tc + 1) * 1024);
        }
      } else { A0 = make_float4(0, 0, 0, 0); A1 = A0; A2 = A0; }

      const float4* r0 = (const float4*)(h1b + cur * 768 + 0 * 256 + kh * 128);
      const float4* r1 = (const float4*)(h1b + cur * 768 + 1 * 256 + kh * 128);
      const float4* r2 = (const float4*)(h1b + cur * 768 + 2 * 256 + kh * 128);

      // register-resident pairs 0..31
      #pragma unroll
      for (int grp = 0; grp < 8; ++grp) {
        float4 h40 = r0[grp], h41 = r1[grp], h42 = r2[grp];
        const v2h* hp0 = (const v2h*)&h40;
        const v2h* hp1 = (const v2h*)&h41;
        const v2h* hp2 = (const v2h*)&h42;
        #pragma unroll
        for (int q = 0; q < 4; ++q) {
          A0 = dot4(wreg[grp * 4 + q], hp0[q], A0);
          A1 = dot4(wreg[grp * 4 + q], hp1[q], A1);
          A2 = dot4(wreg[grp * 4 + q], hp2[q], A2);
        }
      }
      // streamed pairs 32..63
      {
        float4 B[3][4];
        #pragma unroll
        for (int p = 0; p < 4; ++p) {
          B[0][p] = wqS[p * 256];
          B[1][p] = wqS[(4 + p) * 256];
        }
        #pragma unroll
        for (int g = 0; g < 8; ++g) {
          if (g + 2 < 8) {
            #pragma unroll
            for (int p = 0; p < 4; ++p)
              B[(g + 2) % 3][p] = wqS[((g + 2) * 4 + p) * 256];
          }
          const float4* wbuf = B[g % 3];
          float4 h40 = r0[8 + g], h41 = r1[8 + g], h42 = r2[8 + g];
          const v2h* hp0 = (const v2h*)&h40;
          const v2h* hp1 = (const v2h*)&h41;
          const v2h* hp2 = (const v2h*)&h42;
          #pragma unroll
          for (int q = 0; q < 4; ++q) {
            A0 = dot4(wbuf[q], hp0[q], A0);
            A1 = dot4(wbuf[q], hp1[q], A1);
            A2 = dot4(wbuf[q], hp2[q], A2);
          }
        }
      }

      if (kh == 1) {
        #pragma unroll
        for (int g = 0; g < 4; ++g) {
          scratch[u * 13 + g] = ((const float*)&A0)[g];
          scratch[u * 13 + 4 + g] = ((const float*)&A1)[g];
          scratch[u * 13 + 8 + g] = ((const float*)&A2)[g];
        }
      }
      __syncthreads();
      if (kh == 0) {
        float4 B0, B1, B2;
        #pragma unroll
        for (int g = 0; g < 4; ++g) {
          ((float*)&B0)[g] = scratch[u * 13 + g];
          ((float*)&B1)[g] = scratch[u * 13 + 4 + g];
          ((float*)&B2)[g] = scratch[u * 13 + 8 + g];
        }
        A0.x += B0.x; A0.y += B0.y; A0.z += B0.z; A0.w += B0.w;
        A1.x += B1.x; A1.y += B1.y; A1.z += B1.z; A1.w += B1.w;
        A2.x += B2.x; A2.y += B2.y; A2.z += B2.z; A2.w += B2.w;
        float4 A[3] = {A0, A1, A2};
        const int t = kc * Tc + tc;
        #pragma unroll
        for (int b = 0; b < 3; ++b) {
          float ig = sigf(A[b].x), fg = sigf(A[b].y);
          float gg = tanhf_fast(A[b].z), og = sigf(A[b].w);
          c[b] = fg * c[b] + ig * gg;
          float h = og * tanhf_fast(c[b]);
          hout[b] = h;
          h1b[nxt * 768 + b * 256 + u] = __half_as_ushort(__float2half(h));
          if (t == len[b] - 1) ws[OFF_HLAST + (bg + b) * 256 + u] = h;
        }
        xc0 = xn0; xc1 = xn1; xc2 = xn2;
      }
      __syncthreads();
    }
    if (kh == 0) {
      #pragma unroll
      for (int b = 0; b < 3; ++b) {
        ws[OFF_C1S + (bg + b) * 256 + u] = c[b];
        ws[OFF_H1S + (bg + b) * 256 + u] = hout[b];
      }
    }

  } else {
    // ===== role: gemm xp1 = W_ih1 @ h0 + b1, chunk kc = step-1 ============
    if (step < 1 || step >= NCHUNK + 1) return;
    if (bid >= 236) return;
    const int kc = step - 1;
    const int gid = bid - 172;  // [0,64)
    const int b0g = gid * 4;    // 4 batches per block
    const int rt = tid & 63, wv = tid >> 6;
    __half2* hc2 = (__half2*)smem_raw;  // [128 p][128 col]

    int lmax = 0;
    #pragma unroll
    for (int i = 0; i < 4; ++i) lmax = max(lmax, lengths[b0g + i]);
    if (kc * Tc >= lmax) return;
    const int slot = kc & 1;

    {
      const unsigned short* src =
          h0cS + (size_t)slot * H0SLOT + (size_t)b0g * 8192;
      const int cl = tid & 127, pg = tid >> 7;
      #pragma unroll
      for (int pp = 0; pp < 32; pp += 4) {
        const int p0 = pg * 32 + pp;
        uint4 v = *(const uint4*)(src + (size_t)cl * 256 + p0 * 2);
        unsigned* d = (unsigned*)hc2;
        d[(p0 + 0) * 128 + cl] = v.x;
        d[(p0 + 1) * 128 + cl] = v.y;
        d[(p0 + 2) * 128 + cl] = v.z;
        d[(p0 + 3) * 128 + cl] = v.w;
      }
    }
    __syncthreads();

    const __half* Wb = h16 + H_IH1;  // [p][u][g][2]
    unsigned short* xdst = xpS + (size_t)slot * XPSLOT;
    #pragma unroll 1
    for (int rp = 0; rp < 2; ++rp) {
      #pragma unroll 1
      for (int cp = 0; cp < 2; ++cp) {
        const int uA = rp * 128 + rt, uB = uA + 64;
        const int c0 = cp * 64 + wv * 8;
        const float4 bA = ((const float4*)(ws + OFF_B1))[uA];
        const float4 bB = ((const float4*)(ws + OFF_B1))[uB];
        float accA[4][8], accB[4][8];
        #pragma unroll
        for (int g = 0; g < 4; ++g)
          #pragma unroll
          for (int cc = 0; cc < 8; ++cc) {
            accA[g][cc] = ((const float*)&bA)[g];
            accB[g][cc] = ((const float*)&bB)[g];
          }
        #pragma unroll 2
        for (int p = 0; p < 128; ++p) {
          float4 wA = *(const float4*)(Wb + (size_t)p * 2048 + uA * 8);
          float4 wB = *(const float4*)(Wb + (size_t)p * 2048 + uB * 8);
          float4 h0v = *(const float4*)(hc2 + p * 128 + c0);
          float4 h1v = *(const float4*)(hc2 + p * 128 + c0 + 4);
          const v2h* ga = (const v2h*)&wA;
          const v2h* gb = (const v2h*)&wB;
          const v2h* hv = (const v2h*)&h0v;
          const v2h* hw = (const v2h*)&h1v;
          #pragma unroll
          for (int g = 0; g < 4; ++g) {
            #pragma unroll
            for (int cc = 0; cc < 4; ++cc) {
              accA[g][cc] = __builtin_amdgcn_fdot2(ga[g], hv[cc], accA[g][cc], false);
              accA[g][cc + 4] = __builtin_amdgcn_fdot2(ga[g], hw[cc], accA[g][cc + 4], false);
              accB[g][cc] = __builtin_amdgcn_fdot2(gb[g], hv[cc], accB[g][cc], false);
              accB[g][cc + 4] = __builtin_amdgcn_fdot2(gb[g], hw[cc], accB[g][cc + 4], false);
            }
          }
        }
        #pragma unroll
        for (int cc = 0; cc < 8; ++cc) {
          const int col = c0 + cc;
          const size_t cb = ((size_t)(b0g + (col >> 5)) * 32 + (col & 31)) * 1024;
          ushort4 oA, oB;
          oA.x = __half_as_ushort(__float2half(accA[0][cc]));
          oA.y = __half_as_ushort(__float2half(accA[1][cc]));
          oA.z = __half_as_ushort(__float2half(accA[2][cc]));
          oA.w = __half_as_ushort(__float2half(accA[3][cc]));
          oB.x = __half_as_ushort(__float2half(accB[0][cc]));
          oB.y = __half_as_ushort(__float2half(accB[1][cc]));
          oB.z = __half_as_ushort(__float2half(accB[2][cc]));
          oB.w = __half_as_ushort(__float2half(accB[3][cc]));
          *(ushort4*)(xdst + cb + uA * 4) = oA;
          *(ushort4*)(xdst + cb + uB * 4) = oB;
        }
      }
    }
  }
}

__global__ __launch_bounds__(256) void fc_kernel(
    const float* __restrict__ ws, const float* __restrict__ fc_w,
    const float* __restrict__ fc_b, float* __restrict__ out) {
  __shared__ float red[256];
  const int tid = threadIdx.x;
  const int b = blockIdx.x;
  red[tid] = fmaxf(ws[OFF_HLAST + b * 256 + tid], 0.f) * fc_w[tid];
  __syncthreads();
  #pragma unroll
  for (int s = 128; s > 0; s >>= 1) {
    if (tid < s) red[tid] += red[tid + s];
    __syncthreads();
  }
  if (tid == 0) out[b] = red[0] + fc_b[0];
}

extern "C" void kernel_launch(void* const* d_in, const int* in_sizes, int n_in,
                              void* d_out, int out_size, void* d_ws, size_t ws_size,
                              hipStream_t stream) {
  const float* x     = (const float*)d_in[0];
  const int*   lens  = (const int*)d_in[1];
  const float* w_ih0 = (const float*)d_in[2];
  const float* w_hh0 = (const float*)d_in[3];
  const float* b_ih0 = (const float*)d_in[4];
  const float* b_hh0 = (const float*)d_in[5];
  const float* w_ih1 = (const float*)d_in[6];
  const float* w_hh1 = (const float*)d_in[7];
  const float* b_ih1 = (const float*)d_in[8];
  const float* b_hh1 = (const float*)d_in[9];
  const float* fc_w  = (const float*)d_in[10];
  const float* fc_b  = (const float*)d_in[11];
  float* out = (float*)d_out;
  float* ws  = (float*)d_ws;

  hipLaunchKernelGGL(prep_kernel, dim3(512), dim3(256), 0, stream,
                     w_ih0, w_hh0, b_ih0, b_hh0, w_ih1, w_hh1, b_ih1, b_hh1, ws);
  hipFuncSetAttribute(reinterpret_cast<const void*>(fused_kernel),
                      hipFuncAttributeMaxDynamicSharedMemorySize, SMEM_BYTES);
  for (int k = 0; k < NCHUNK + 2; ++k) {
    hipLaunchKernelGGL(fused_kernel, dim3(236), dim3(512), SMEM_BYTES, stream,
                       ws, x, lens, k);
  }
  hipLaunchKernelGGL(fc_kernel, dim3(256), dim3(256), 0, stream,
                     ws, fc_w, fc_b, out);
}